// Round 4
// baseline (418.601 us; speedup 1.0000x reference)
//
#include <hip/hip_runtime.h>
#include <math.h>

// GMM EM, M=4 mixtures x G=4 gaussians, C=3, EM_ITERS=3, EPS=1e-4.
// R4: 4 dispatches: accum0 -> accum1 -> accum2 -> final. Each accum kernel's
// LAST block (ticket via device-scope atomicAdd after __threadfence) reduces
// the per-block partials and computes the 16 cluster params inline -- removes
// the 3 single-block k_params dispatches and their drain/refill bubbles.
// Params ping-pong across 3 buffers (a not-yet-started block must never read
// freshly written params). Stats accumulation keeps R3's verified
// wave-synchronous LDS transpose (zero atomics, zero bank conflicts).

#define NTHR  256
#define NBLK  512
#define EPS_F 1e-4f
#define LOG2PI3 5.5136311992280366f   // 3*ln(2*pi)

// ---------- fused stats kernel: mode 0 = init (g = n%4), mode 1 = E+M step ----
// partials layout: [block][160] (row-major, coalesced write & reduce read)
__global__ __launch_bounds__(NTHR) void k_accum(const float* __restrict__ x,
                                                const int* __restrict__ lab,
                                                const float* __restrict__ paramsIn,
                                                float* __restrict__ paramsOut,
                                                float* __restrict__ partials,
                                                int* __restrict__ ticket,
                                                int N, int mode) {
    __shared__ __align__(16) float stage[NTHR / 64][64][8];  // wave-private slabs
    __shared__ __align__(16) float spar[192];
    __shared__ float red[NTHR / 64][160];
    __shared__ float sums[160];
    __shared__ float wtab[16];
    __shared__ int   lastFlag;
    const int tid  = threadIdx.x;
    const int wave = tid >> 6, lane = tid & 63;
    const int t  = lane >> 2, p = lane & 3;   // cluster t = m*4+g, pixel phase p
    const int tm = t >> 2,  tg = t & 3;
    if (mode && tid < 192) spar[tid] = paramsIn[tid];
    __syncthreads();

    float acc[10];
    #pragma unroll
    for (int k = 0; k < 10; ++k) acc[k] = 0.f;

    const int groups = N >> 2;
    const int stride = gridDim.x * NTHR;
    const int gid    = blockIdx.x * NTHR + tid;
    const int trips  = (groups + stride - 1) / stride;
    const float4* x0p = (const float4*)x;
    const float4* x1p = (const float4*)(x + N);
    const float4* x2p = (const float4*)(x + 2 * N);
    const int4*   lp  = (const int4*)lab;

    for (int tr = 0; tr < trips; ++tr) {
        const int i  = tr * stride + gid;
        const bool valid = i < groups;
        const int ii = valid ? i : (groups - 1);
        float4 va = x0p[ii], vb = x1p[ii], vc = x2p[ii];
        int4   m4 = lp[ii];
        float pa[4] = {va.x, va.y, va.z, va.w};
        float pb[4] = {vb.x, vb.y, vb.z, vb.w};
        float pc[4] = {vc.x, vc.y, vc.z, vc.w};
        int   pm[4] = {m4.x, m4.y, m4.z, m4.w};
        if (!valid) { pm[0] = pm[1] = pm[2] = pm[3] = -1; }

        #pragma unroll
        for (int j = 0; j < 4; ++j) {      // pixel n = 4*i + j  ->  n%4 = j
            const float a = pa[j], b = pb[j], c = pc[j];
            const int   m = pm[j];
            float w0, w1, w2, w3;
            if (mode) {
                const float* P0 = spar + (m & 3) * 48;
                float l[4];
                #pragma unroll
                for (int g = 0; g < 4; ++g) {
                    const float* P = P0 + g * 12;
                    float4 q0 = *(const float4*)(P);
                    float4 q1 = *(const float4*)(P + 4);
                    float2 q2 = *(const float2*)(P + 8);
                    l[g] = q0.w + q0.x * a + q0.y * b + q0.z * c
                         + q1.x * (a * a) + q1.y * (b * b) + q1.z * (c * c)
                         + q1.w * (a * b) + q2.x * (a * c) + q2.y * (b * c);
                }
                float mx = fmaxf(fmaxf(l[0], l[1]), fmaxf(l[2], l[3]));
                float e0 = __expf(l[0] - mx), e1 = __expf(l[1] - mx);
                float e2 = __expf(l[2] - mx), e3 = __expf(l[3] - mx);
                float rs = 1.0f / (e0 + e1 + e2 + e3);
                w0 = e0 * rs; w1 = e1 * rs; w2 = e2 * rs; w3 = e3 * rs;
            } else {
                w0 = (j == 0) ? 1.f : 0.f; w1 = (j == 1) ? 1.f : 0.f;
                w2 = (j == 2) ? 1.f : 0.f; w3 = (j == 3) ? 1.f : 0.f;
            }
            float* sl = &stage[wave][lane][0];
            ((float4*)sl)[0] = make_float4(w0, w1, w2, w3);
            ((float4*)sl)[1] = make_float4(a, b, c, __int_as_float(m));
            __builtin_amdgcn_wave_barrier();   // keep write->read order (0 instr)
            #pragma unroll
            for (int it = 0; it < 16; ++it) {
                const float* sq = &stage[wave][p + 4 * it][0];
                float  wv = sq[tg];
                float4 r  = ((const float4*)sq)[1];
                float sel = (__float_as_int(r.w) == tm) ? wv : 0.f;
                float sa = sel * r.x, sb = sel * r.y, sc = sel * r.z;
                acc[0] += sel;
                acc[1] = fmaf(sel, r.x, acc[1]);
                acc[2] = fmaf(sel, r.y, acc[2]);
                acc[3] = fmaf(sel, r.z, acc[3]);
                acc[4] = fmaf(sa, r.x, acc[4]);
                acc[5] = fmaf(sa, r.y, acc[5]);
                acc[6] = fmaf(sa, r.z, acc[6]);
                acc[7] = fmaf(sb, r.y, acc[7]);
                acc[8] = fmaf(sb, r.z, acc[8]);
                acc[9] = fmaf(sc, r.z, acc[9]);
            }
            __builtin_amdgcn_wave_barrier();   // keep read->next-write order
        }
    }

    // reduce over p (4 lanes per cluster) then across waves -> one 160-row
    #pragma unroll
    for (int k = 0; k < 10; ++k) {
        acc[k] += __shfl_xor(acc[k], 1, 64);
        acc[k] += __shfl_xor(acc[k], 2, 64);
    }
    if (p == 0) {
        #pragma unroll
        for (int k = 0; k < 10; ++k) red[wave][t * 10 + k] = acc[k];
    }
    __syncthreads();
    if (tid < 160) {
        float s = red[0][tid] + red[1][tid] + red[2][tid] + red[3][tid];
        partials[(size_t)blockIdx.x * 160 + tid] = s;   // coalesced row
    }

    // ---- ticket: last block reduces partials + computes params ----
    __threadfence();                               // release partial row (L2 wb)
    if (tid == 0) {
        int tk = atomicAdd(ticket, 1);             // device-scope
        lastFlag = (tk == (int)gridDim.x - 1);
    }
    __syncthreads();
    if (!lastFlag) return;
    __threadfence();                               // acquire (L2 inv)

    const int nb = gridDim.x;
    if (tid < 160) {
        float s = 0.f;
        for (int b2 = 0; b2 < nb; b2 += 2)         // 2-deep MLP unroll
            s += partials[(size_t)b2 * 160 + tid]
               + partials[(size_t)(b2 + 1) * 160 + tid];
        sums[tid] = s;
    }
    __syncthreads();
    if (tid < 16) wtab[tid] = sums[tid * 10] + EPS_F;
    __syncthreads();
    if (tid < 16) {
        const int tt = tid;
        const float* S = &sums[tt * 10];
        const float w  = wtab[tt];
        const float iw = 1.0f / w;
        float mu0 = S[1] * iw, mu1 = S[2] * iw, mu2 = S[3] * iw;
        float c00 = S[4] * iw - mu0 * mu0 + EPS_F;
        float c01 = S[5] * iw - mu0 * mu1;
        float c02 = S[6] * iw - mu0 * mu2;
        float c11 = S[7] * iw - mu1 * mu1 + EPS_F;
        float c12 = S[8] * iw - mu1 * mu2;
        float c22 = S[9] * iw - mu2 * mu2 + EPS_F;
        float d00 = c11 * c22 - c12 * c12;
        float d01 = c02 * c12 - c01 * c22;
        float d02 = c01 * c12 - c02 * c11;
        float det = c00 * d00 + c01 * d01 + c02 * d02;
        float idet = 1.0f / det;
        float P00 = d00 * idet, P01 = d01 * idet, P02 = d02 * idet;
        float P11 = (c00 * c22 - c02 * c02) * idet;
        float P12 = (c01 * c02 - c00 * c12) * idet;
        float P22 = (c00 * c11 - c01 * c01) * idet;
        float logdet = logf(det);
        const int mb = tt & 12;
        float wsum = wtab[mb] + wtab[mb + 1] + wtab[mb + 2] + wtab[mb + 3];
        float logpi = logf(w) - logf(wsum);
        float pm0 = P00 * mu0 + P01 * mu1 + P02 * mu2;
        float pm1 = P01 * mu0 + P11 * mu1 + P12 * mu2;
        float pm2 = P02 * mu0 + P12 * mu1 + P22 * mu2;
        float mPm = mu0 * pm0 + mu1 * pm1 + mu2 * pm2;
        float c0 = logpi - 0.5f * (mPm + logdet + LOG2PI3);
        float* P = paramsOut + tt * 12;
        P[0] = pm0; P[1] = pm1; P[2] = pm2; P[3] = c0;
        P[4] = -0.5f * P00; P[5] = -0.5f * P11; P[6] = -0.5f * P22;
        P[7] = -P01; P[8] = -P02; P[9] = -P12;
        P[10] = 0.f; P[11] = 0.f;
    }
}

// ---------- final: logp for all 16 gaussians -> logsumexp_g -> softmax_m ----------
static __device__ __forceinline__ void final_pixel(const float* __restrict__ PR,
                                                   float a, float b, float c,
                                                   float* post) {
    float xx00 = a * a, xx01 = a * b, xx02 = a * c;
    float xx11 = b * b, xx12 = b * c, xx22 = c * c;
    float ml[4];
    #pragma unroll
    for (int m = 0; m < 4; ++m) {
        float l[4];
        #pragma unroll
        for (int g = 0; g < 4; ++g) {
            const float* P = PR + (m * 4 + g) * 10;
            l[g] = P[3] + P[0] * a + P[1] * b + P[2] * c
                 + P[4] * xx00 + P[5] * xx11 + P[6] * xx22
                 + P[7] * xx01 + P[8] * xx02 + P[9] * xx12;
        }
        float mx = fmaxf(fmaxf(l[0], l[1]), fmaxf(l[2], l[3]));
        ml[m] = mx + __logf(__expf(l[0] - mx) + __expf(l[1] - mx)
                          + __expf(l[2] - mx) + __expf(l[3] - mx));
    }
    float mmx = fmaxf(fmaxf(ml[0], ml[1]), fmaxf(ml[2], ml[3]));
    float e0 = __expf(ml[0] - mmx), e1 = __expf(ml[1] - mmx);
    float e2 = __expf(ml[2] - mmx), e3 = __expf(ml[3] - mmx);
    float rs = 1.0f / (e0 + e1 + e2 + e3);
    post[0] = e0 * rs; post[1] = e1 * rs; post[2] = e2 * rs; post[3] = e3 * rs;
}

__global__ __launch_bounds__(NTHR) void k_final(const float* __restrict__ x,
                                                const float* __restrict__ params,
                                                float* __restrict__ out,
                                                int N) {
    __shared__ __align__(16) float spar[192];
    if (threadIdx.x < 192) spar[threadIdx.x] = params[threadIdx.x];
    __syncthreads();
    float PR[160];
    #pragma unroll
    for (int t = 0; t < 16; ++t) {
        #pragma unroll
        for (int k = 0; k < 10; ++k) PR[t * 10 + k] = spar[t * 12 + k];
    }
    const int groups = N >> 2;
    const float4* x0p = (const float4*)x;
    const float4* x1p = (const float4*)(x + N);
    const float4* x2p = (const float4*)(x + 2 * N);
    const int stride = gridDim.x * NTHR;
    for (int i = blockIdx.x * NTHR + threadIdx.x; i < groups; i += stride) {
        float4 a = x0p[i], b = x1p[i], c = x2p[i];
        float p0[4], p1[4], p2[4], p3[4];
        final_pixel(PR, a.x, b.x, c.x, p0);
        final_pixel(PR, a.y, b.y, c.y, p1);
        final_pixel(PR, a.z, b.z, c.z, p2);
        final_pixel(PR, a.w, b.w, c.w, p3);
        #pragma unroll
        for (int m = 0; m < 4; ++m) {
            ((float4*)(out + (size_t)m * N))[i] =
                make_float4(p0[m], p1[m], p2[m], p3[m]);
        }
    }
}

extern "C" void kernel_launch(void* const* d_in, const int* in_sizes, int n_in,
                              void* d_out, int out_size, void* d_ws, size_t ws_size,
                              hipStream_t stream) {
    const float* x   = (const float*)d_in[0];   // [3, N] float32
    const int*   lab = (const int*)d_in[1];     // [N] int32 in [0,4)
    float* out = (float*)d_out;                 // [4, N] float32
    const int N = in_sizes[1];

    int nb = NBLK;
    while (nb > 64 && ws_size < (size_t)(160 * nb + 3 * 192 + 16) * sizeof(float))
        nb >>= 1;
    float* partials = (float*)d_ws;                    // [nb][160]
    float* params   = partials + (size_t)160 * nb;     // [3][192] ping-pong
    int*   tickets  = (int*)(params + 3 * 192);        // [3]

    hipMemsetAsync(tickets, 0, 3 * sizeof(int), stream);

    dim3 grid(nb), blk(NTHR);
    k_accum<<<grid, blk, 0, stream>>>(x, lab, params, params,
                                      partials, tickets + 0, N, 0);
    k_accum<<<grid, blk, 0, stream>>>(x, lab, params, params + 192,
                                      partials, tickets + 1, N, 1);
    k_accum<<<grid, blk, 0, stream>>>(x, lab, params + 192, params + 384,
                                      partials, tickets + 2, N, 1);
    k_final<<<grid, blk, 0, stream>>>(x, params + 384, out, N);
}

// Round 5
// 234.240 us; speedup vs baseline: 1.7871x; 1.7871x over previous
//
#include <hip/hip_runtime.h>
#include <math.h>

// GMM EM, M=4 mixtures x G=4 gaussians, C=3, EM_ITERS=3, EPS=1e-4.
// R5: register-accumulator rewrite. R3/R4 proved the wave-synchronous LDS
// transpose is latency-bound (~50-120us, VALUBusy 8%). Now each thread holds
// all 16 clusters x 10 stats in VGPRs and does a branchless masked accumulate
// (16 cndmask + 160 FMA per pixel, zero LDS in the hot loop). Cross-block
// combine via hardware global_atomic_add_f32 (unsafeAtomicAdd on GLOBAL
// pointers -- the R2 CAS failure was the LDS/generic path), 4-banked to cap
// same-address contention. No partials matrix, no ticket tail: every block of
// the NEXT dispatch redundantly derives the 16x12 params from the 160 sums.
// Pipeline: memset(7.7KB) -> accum0 -> accum1 -> accum2 -> final.

#define NTHR  256
#define NBLK  512
#define EPS_F 1e-4f
#define LOG2PI3 5.5136311992280366f   // 3*ln(2*pi)

// sums buffer per pass: [160 slots][4 banks] floats (slot = t*10+k)

// Derive E-step params from banked sums. spar layout per cluster t, stride 12:
// [0..2]=P*mu, [3]=c0, [4..6]=-0.5*Pii, [7..9]=-Pij(01,02,12), [10..11]=pad
static __device__ void compute_params(const float* __restrict__ sumsIn,
                                      float* spar, float* sums, float* wtab,
                                      int tid) {
    if (tid < 160) {
        float4 v = ((const float4*)sumsIn)[tid];   // 4 banks -> horizontal add
        sums[tid] = (v.x + v.y) + (v.z + v.w);
    }
    __syncthreads();
    if (tid < 16) wtab[tid] = sums[tid * 10] + EPS_F;
    __syncthreads();
    if (tid < 16) {
        const int tt = tid;
        const float* S = &sums[tt * 10];
        const float w  = wtab[tt];
        const float iw = 1.0f / w;
        float mu0 = S[1] * iw, mu1 = S[2] * iw, mu2 = S[3] * iw;
        float c00 = S[4] * iw - mu0 * mu0 + EPS_F;
        float c01 = S[5] * iw - mu0 * mu1;
        float c02 = S[6] * iw - mu0 * mu2;
        float c11 = S[7] * iw - mu1 * mu1 + EPS_F;
        float c12 = S[8] * iw - mu1 * mu2;
        float c22 = S[9] * iw - mu2 * mu2 + EPS_F;
        float d00 = c11 * c22 - c12 * c12;
        float d01 = c02 * c12 - c01 * c22;
        float d02 = c01 * c12 - c02 * c11;
        float det = c00 * d00 + c01 * d01 + c02 * d02;
        float idet = 1.0f / det;
        float P00 = d00 * idet, P01 = d01 * idet, P02 = d02 * idet;
        float P11 = (c00 * c22 - c02 * c02) * idet;
        float P12 = (c01 * c02 - c00 * c12) * idet;
        float P22 = (c00 * c11 - c01 * c01) * idet;
        float logdet = logf(det);
        const int mb = tt & 12;
        float wsum = wtab[mb] + wtab[mb + 1] + wtab[mb + 2] + wtab[mb + 3];
        float logpi = logf(w) - logf(wsum);
        float pm0 = P00 * mu0 + P01 * mu1 + P02 * mu2;
        float pm1 = P01 * mu0 + P11 * mu1 + P12 * mu2;
        float pm2 = P02 * mu0 + P12 * mu1 + P22 * mu2;
        float mPm = mu0 * pm0 + mu1 * pm1 + mu2 * pm2;
        float c0 = logpi - 0.5f * (mPm + logdet + LOG2PI3);
        float* P = spar + tt * 12;
        P[0] = pm0; P[1] = pm1; P[2] = pm2; P[3] = c0;
        P[4] = -0.5f * P00; P[5] = -0.5f * P11; P[6] = -0.5f * P22;
        P[7] = -P01; P[8] = -P02; P[9] = -P12;
        P[10] = 0.f; P[11] = 0.f;
    }
    __syncthreads();
}

// ---------- stats kernel: mode 0 = init (g = n%4), mode 1 = E+M step ----------
__global__ __launch_bounds__(NTHR, 2) void k_accum(const float* __restrict__ x,
                                                   const int* __restrict__ lab,
                                                   const float* __restrict__ sumsIn,
                                                   float* __restrict__ sumsOut,
                                                   int N, int mode) {
    __shared__ __align__(16) float spar[192];
    __shared__ float sums[160];
    __shared__ float wtab[16];
    __shared__ float sred[NTHR / 64][160];
    const int tid  = threadIdx.x;
    const int wave = tid >> 6, lane = tid & 63;
    if (mode) compute_params(sumsIn, spar, sums, wtab, tid);

    float acc[160];
    #pragma unroll
    for (int k = 0; k < 160; ++k) acc[k] = 0.f;

    const int groups = N >> 2;
    const int stride = gridDim.x * NTHR;
    const int gid    = blockIdx.x * NTHR + tid;
    const int trips  = (groups + stride - 1) / stride;
    const float4* x0p = (const float4*)x;
    const float4* x1p = (const float4*)(x + N);
    const float4* x2p = (const float4*)(x + 2 * N);
    const int4*   lp  = (const int4*)lab;

    for (int tr = 0; tr < trips; ++tr) {
        const int i  = tr * stride + gid;
        const bool valid = i < groups;
        const int ii = valid ? i : 0;
        float4 va = x0p[ii], vb = x1p[ii], vc = x2p[ii];
        int4   m4 = lp[ii];
        float pa[4] = {va.x, va.y, va.z, va.w};
        float pb[4] = {vb.x, vb.y, vb.z, vb.w};
        float pc[4] = {vc.x, vc.y, vc.z, vc.w};
        int   pm[4] = {m4.x, m4.y, m4.z, m4.w};
        if (!valid) { pm[0] = pm[1] = pm[2] = pm[3] = -1; }

        #pragma unroll
        for (int j = 0; j < 4; ++j) {      // pixel n = 4*i + j  ->  n%4 = j
            const float a = pa[j], b = pb[j], c = pc[j];
            const int   m = pm[j];
            float ws[4];
            if (mode) {
                const float* P0 = spar + (m & 3) * 48;
                float l[4];
                #pragma unroll
                for (int g = 0; g < 4; ++g) {
                    const float* P = P0 + g * 12;
                    float4 q0 = *(const float4*)(P);
                    float4 q1 = *(const float4*)(P + 4);
                    float2 q2 = *(const float2*)(P + 8);
                    l[g] = q0.w + q0.x * a + q0.y * b + q0.z * c
                         + q1.x * (a * a) + q1.y * (b * b) + q1.z * (c * c)
                         + q1.w * (a * b) + q2.x * (a * c) + q2.y * (b * c);
                }
                float mx = fmaxf(fmaxf(l[0], l[1]), fmaxf(l[2], l[3]));
                float e0 = __expf(l[0] - mx), e1 = __expf(l[1] - mx);
                float e2 = __expf(l[2] - mx), e3 = __expf(l[3] - mx);
                float rs = 1.0f / (e0 + e1 + e2 + e3);
                ws[0] = e0 * rs; ws[1] = e1 * rs; ws[2] = e2 * rs; ws[3] = e3 * rs;
            } else {
                ws[0] = (j == 0) ? 1.f : 0.f; ws[1] = (j == 1) ? 1.f : 0.f;
                ws[2] = (j == 2) ? 1.f : 0.f; ws[3] = (j == 3) ? 1.f : 0.f;
            }
            // moments
            const float aa = a * a, ab = a * b, ac = a * c;
            const float bb = b * b, bc = b * c, cc = c * c;
            // branchless masked accumulate into all 16 clusters
            #pragma unroll
            for (int mm = 0; mm < 4; ++mm) {
                const bool sel = (m == mm);
                #pragma unroll
                for (int g = 0; g < 4; ++g) {
                    const float s = sel ? ws[g] : 0.f;
                    float* A = &acc[(mm * 4 + g) * 10];
                    A[0] += s;
                    A[1] = fmaf(s, a,  A[1]);
                    A[2] = fmaf(s, b,  A[2]);
                    A[3] = fmaf(s, c,  A[3]);
                    A[4] = fmaf(s, aa, A[4]);
                    A[5] = fmaf(s, ab, A[5]);
                    A[6] = fmaf(s, ac, A[6]);
                    A[7] = fmaf(s, bb, A[7]);
                    A[8] = fmaf(s, bc, A[8]);
                    A[9] = fmaf(s, cc, A[9]);
                }
            }
        }
    }

    // wave reduce each slot to lane 0, stash in LDS
    #pragma unroll
    for (int k = 0; k < 160; ++k) {
        float v = acc[k];
        v += __shfl_down(v, 32, 64);
        v += __shfl_down(v, 16, 64);
        v += __shfl_down(v,  8, 64);
        v += __shfl_down(v,  4, 64);
        v += __shfl_down(v,  2, 64);
        v += __shfl_down(v,  1, 64);
        if (lane == 0) sred[wave][k] = v;
    }
    __syncthreads();
    if (tid < 160) {
        float s = sred[0][tid] + sred[1][tid] + sred[2][tid] + sred[3][tid];
        unsafeAtomicAdd(&sumsOut[tid * 4 + (blockIdx.x & 3)], s);  // global HW fadd
    }
}

// ---------- final: logp for all 16 gaussians -> logsumexp_g -> softmax_m ----------
static __device__ __forceinline__ void final_pixel(const float* __restrict__ PR,
                                                   float a, float b, float c,
                                                   float* post) {
    float xx00 = a * a, xx01 = a * b, xx02 = a * c;
    float xx11 = b * b, xx12 = b * c, xx22 = c * c;
    float ml[4];
    #pragma unroll
    for (int m = 0; m < 4; ++m) {
        float l[4];
        #pragma unroll
        for (int g = 0; g < 4; ++g) {
            const float* P = PR + (m * 4 + g) * 10;
            l[g] = P[3] + P[0] * a + P[1] * b + P[2] * c
                 + P[4] * xx00 + P[5] * xx11 + P[6] * xx22
                 + P[7] * xx01 + P[8] * xx02 + P[9] * xx12;
        }
        float mx = fmaxf(fmaxf(l[0], l[1]), fmaxf(l[2], l[3]));
        ml[m] = mx + __logf(__expf(l[0] - mx) + __expf(l[1] - mx)
                          + __expf(l[2] - mx) + __expf(l[3] - mx));
    }
    float mmx = fmaxf(fmaxf(ml[0], ml[1]), fmaxf(ml[2], ml[3]));
    float e0 = __expf(ml[0] - mmx), e1 = __expf(ml[1] - mmx);
    float e2 = __expf(ml[2] - mmx), e3 = __expf(ml[3] - mmx);
    float rs = 1.0f / (e0 + e1 + e2 + e3);
    post[0] = e0 * rs; post[1] = e1 * rs; post[2] = e2 * rs; post[3] = e3 * rs;
}

__global__ __launch_bounds__(NTHR, 2) void k_final(const float* __restrict__ x,
                                                   const float* __restrict__ sumsIn,
                                                   float* __restrict__ out,
                                                   int N) {
    __shared__ __align__(16) float spar[192];
    __shared__ float sums[160];
    __shared__ float wtab[16];
    compute_params(sumsIn, spar, sums, wtab, threadIdx.x);
    // hoist params into registers (static indexing after full unroll)
    float PR[160];
    #pragma unroll
    for (int t = 0; t < 16; ++t) {
        #pragma unroll
        for (int k = 0; k < 10; ++k) PR[t * 10 + k] = spar[t * 12 + k];
    }
    const int groups = N >> 2;
    const float4* x0p = (const float4*)x;
    const float4* x1p = (const float4*)(x + N);
    const float4* x2p = (const float4*)(x + 2 * N);
    const int stride = gridDim.x * NTHR;
    for (int i = blockIdx.x * NTHR + threadIdx.x; i < groups; i += stride) {
        float4 a = x0p[i], b = x1p[i], c = x2p[i];
        float p0[4], p1[4], p2[4], p3[4];
        final_pixel(PR, a.x, b.x, c.x, p0);
        final_pixel(PR, a.y, b.y, c.y, p1);
        final_pixel(PR, a.z, b.z, c.z, p2);
        final_pixel(PR, a.w, b.w, c.w, p3);
        #pragma unroll
        for (int m = 0; m < 4; ++m) {
            ((float4*)(out + (size_t)m * N))[i] =
                make_float4(p0[m], p1[m], p2[m], p3[m]);
        }
    }
}

extern "C" void kernel_launch(void* const* d_in, const int* in_sizes, int n_in,
                              void* d_out, int out_size, void* d_ws, size_t ws_size,
                              hipStream_t stream) {
    const float* x   = (const float*)d_in[0];   // [3, N] float32
    const int*   lab = (const int*)d_in[1];     // [N] int32 in [0,4)
    float* out = (float*)d_out;                 // [4, N] float32
    const int N = in_sizes[1];

    float* sums = (float*)d_ws;                 // [3 passes][160 slots][4 banks]
    hipMemsetAsync(sums, 0, 3 * 640 * sizeof(float), stream);

    dim3 grid(NBLK), blk(NTHR);
    k_accum<<<grid, blk, 0, stream>>>(x, lab, sums, sums, N, 0);
    k_accum<<<grid, blk, 0, stream>>>(x, lab, sums, sums + 640, N, 1);
    k_accum<<<grid, blk, 0, stream>>>(x, lab, sums + 640, sums + 1280, N, 1);
    k_final<<<grid, blk, 0, stream>>>(x, sums + 1280, out, N);
}

// Round 6
// 151.661 us; speedup vs baseline: 2.7601x; 1.5445x over previous
//
#include <hip/hip_runtime.h>
#include <math.h>

// GMM EM, M=4 mixtures x G=4 gaussians, C=3, EM_ITERS=3, EPS=1e-4.
// R6: quad-role split to kill the R5 register spill (VGPR=128 vs 160-elem
// arrays -> scratch: k_final WRITE 35MB vs 16MB output, VALUBusy 0.4%).
// Lane role q = lane&3 owns mixture q only: acc[40] / params[40] in regs.
// Pixels are quad-broadcast via shuffles; masked accumulate (cndmask+FMA).
// Cross-block combine stays: shfl_xor reduce -> LDS -> banked global
// unsafeAtomicAdd (HW global_atomic_add_f32, verified R5). Every block of the
// next dispatch redundantly derives the 16x12 params from the 160 sums.
// Pipeline: memset(7.7KB) -> accum0 -> accum1 -> accum2 -> final.

#define NTHR  256
#define NBLK  512
#define EPS_F 1e-4f
#define LOG2PI3 5.5136311992280366f   // 3*ln(2*pi)

// sums buffer per pass: [160 slots][4 banks] floats (slot = t*10+k)

// Derive E-step params from banked sums. spar layout per cluster t, stride 12:
// [0..2]=P*mu, [3]=c0, [4..6]=-0.5*Pii, [7..9]=-Pij(01,02,12), [10..11]=pad
static __device__ void compute_params(const float* __restrict__ sumsIn,
                                      float* spar, float* sums, float* wtab,
                                      int tid) {
    if (tid < 160) {
        float4 v = ((const float4*)sumsIn)[tid];   // 4 banks -> horizontal add
        sums[tid] = (v.x + v.y) + (v.z + v.w);
    }
    __syncthreads();
    if (tid < 16) wtab[tid] = sums[tid * 10] + EPS_F;
    __syncthreads();
    if (tid < 16) {
        const int tt = tid;
        const float* S = &sums[tt * 10];
        const float w  = wtab[tt];
        const float iw = 1.0f / w;
        float mu0 = S[1] * iw, mu1 = S[2] * iw, mu2 = S[3] * iw;
        float c00 = S[4] * iw - mu0 * mu0 + EPS_F;
        float c01 = S[5] * iw - mu0 * mu1;
        float c02 = S[6] * iw - mu0 * mu2;
        float c11 = S[7] * iw - mu1 * mu1 + EPS_F;
        float c12 = S[8] * iw - mu1 * mu2;
        float c22 = S[9] * iw - mu2 * mu2 + EPS_F;
        float d00 = c11 * c22 - c12 * c12;
        float d01 = c02 * c12 - c01 * c22;
        float d02 = c01 * c12 - c02 * c11;
        float det = c00 * d00 + c01 * d01 + c02 * d02;
        float idet = 1.0f / det;
        float P00 = d00 * idet, P01 = d01 * idet, P02 = d02 * idet;
        float P11 = (c00 * c22 - c02 * c02) * idet;
        float P12 = (c01 * c02 - c00 * c12) * idet;
        float P22 = (c00 * c11 - c01 * c01) * idet;
        float logdet = logf(det);
        const int mb = tt & 12;
        float wsum = wtab[mb] + wtab[mb + 1] + wtab[mb + 2] + wtab[mb + 3];
        float logpi = logf(w) - logf(wsum);
        float pm0 = P00 * mu0 + P01 * mu1 + P02 * mu2;
        float pm1 = P01 * mu0 + P11 * mu1 + P12 * mu2;
        float pm2 = P02 * mu0 + P12 * mu1 + P22 * mu2;
        float mPm = mu0 * pm0 + mu1 * pm1 + mu2 * pm2;
        float c0 = logpi - 0.5f * (mPm + logdet + LOG2PI3);
        float* P = spar + tt * 12;
        P[0] = pm0; P[1] = pm1; P[2] = pm2; P[3] = c0;
        P[4] = -0.5f * P00; P[5] = -0.5f * P11; P[6] = -0.5f * P22;
        P[7] = -P01; P[8] = -P02; P[9] = -P12;
        P[10] = 0.f; P[11] = 0.f;
    }
    __syncthreads();
}

// ---------- stats kernel: mode 0 = init (g = n%4), mode 1 = E+M step ----------
__global__ __launch_bounds__(NTHR, 2) void k_accum(const float* __restrict__ x,
                                                   const int* __restrict__ lab,
                                                   const float* __restrict__ sumsIn,
                                                   float* __restrict__ sumsOut,
                                                   int N, int mode) {
    __shared__ __align__(16) float spar[192];
    __shared__ float sums[160];
    __shared__ float wtab[16];
    __shared__ float sred[NTHR / 64][160];
    const int tid  = threadIdx.x;
    const int wave = tid >> 6, lane = tid & 63;
    const int q    = lane & 3;          // my role: mixture q
    const int qb   = lane & ~3;         // quad base lane
    if (mode) compute_params(sumsIn, spar, sums, wtab, tid);

    float acc[40];                      // mixture q: 4 gaussians x 10 stats
    #pragma unroll
    for (int k = 0; k < 40; ++k) acc[k] = 0.f;

    const int groups = N >> 2;
    const int stride = gridDim.x * NTHR;
    const int gid    = blockIdx.x * NTHR + tid;
    const int trips  = (groups + stride - 1) / stride;
    const float4* x0p = (const float4*)x;
    const float4* x1p = (const float4*)(x + N);
    const float4* x2p = (const float4*)(x + 2 * N);
    const int4*   lp  = (const int4*)lab;

    for (int tr = 0; tr < trips; ++tr) {
        const int i  = tr * stride + gid;
        const bool valid = i < groups;
        const int ii = valid ? i : 0;
        float4 va = x0p[ii], vb = x1p[ii], vc = x2p[ii];
        int4   m4 = lp[ii];
        float pa[4] = {va.x, va.y, va.z, va.w};
        float pb[4] = {vb.x, vb.y, vb.z, vb.w};
        float pc[4] = {vc.x, vc.y, vc.z, vc.w};
        int   pm[4] = {m4.x, m4.y, m4.z, m4.w};
        if (!valid) { pm[0] = pm[1] = pm[2] = pm[3] = -1; }

        #pragma unroll
        for (int j = 0; j < 4; ++j) {      // pixel n = 4*i + j  ->  n%4 = j
            const float a = pa[j], b = pb[j], c = pc[j];
            const int   m = pm[j];
            float ws[4] = {0.f, 0.f, 0.f, 0.f};
            if (mode) {
                // E-step for my own pixel (params of its mixture from LDS)
                const float* P0 = spar + (m & 3) * 48;
                float l[4];
                #pragma unroll
                for (int g = 0; g < 4; ++g) {
                    const float* P = P0 + g * 12;
                    float4 q0 = *(const float4*)(P);
                    float4 q1 = *(const float4*)(P + 4);
                    float2 q2 = *(const float2*)(P + 8);
                    l[g] = q0.w + q0.x * a + q0.y * b + q0.z * c
                         + q1.x * (a * a) + q1.y * (b * b) + q1.z * (c * c)
                         + q1.w * (a * b) + q2.x * (a * c) + q2.y * (b * c);
                }
                float mx = fmaxf(fmaxf(l[0], l[1]), fmaxf(l[2], l[3]));
                float e0 = __expf(l[0] - mx), e1 = __expf(l[1] - mx);
                float e2 = __expf(l[2] - mx), e3 = __expf(l[3] - mx);
                float rs = 1.0f / (e0 + e1 + e2 + e3);
                ws[0] = e0 * rs; ws[1] = e1 * rs; ws[2] = e2 * rs; ws[3] = e3 * rs;
            }
            // quad-broadcast each lane's pixel; role lane accumulates masked
            #pragma unroll
            for (int src = 0; src < 4; ++src) {
                const float ra = __shfl(a, qb + src, 64);
                const float rb = __shfl(b, qb + src, 64);
                const float rc = __shfl(c, qb + src, 64);
                const int   rm = __shfl(m, qb + src, 64);
                const bool sel = (rm == q);
                const float aa = ra * ra, ab = ra * rb, ac = ra * rc;
                const float bb = rb * rb, bc = rb * rc, cc = rc * rc;
                if (mode) {
                    float rw[4];
                    rw[0] = __shfl(ws[0], qb + src, 64);
                    rw[1] = __shfl(ws[1], qb + src, 64);
                    rw[2] = __shfl(ws[2], qb + src, 64);
                    rw[3] = __shfl(ws[3], qb + src, 64);
                    #pragma unroll
                    for (int g = 0; g < 4; ++g) {
                        const float s = sel ? rw[g] : 0.f;
                        float* A = &acc[g * 10];
                        A[0] += s;
                        A[1] = fmaf(s, ra, A[1]);
                        A[2] = fmaf(s, rb, A[2]);
                        A[3] = fmaf(s, rc, A[3]);
                        A[4] = fmaf(s, aa, A[4]);
                        A[5] = fmaf(s, ab, A[5]);
                        A[6] = fmaf(s, ac, A[6]);
                        A[7] = fmaf(s, bb, A[7]);
                        A[8] = fmaf(s, bc, A[8]);
                        A[9] = fmaf(s, cc, A[9]);
                    }
                } else {
                    // init: w = onehot(g = n%4 = j); only gaussian j updates
                    const float s = sel ? 1.f : 0.f;
                    float* A = &acc[j * 10];
                    A[0] += s;
                    A[1] = fmaf(s, ra, A[1]);
                    A[2] = fmaf(s, rb, A[2]);
                    A[3] = fmaf(s, rc, A[3]);
                    A[4] = fmaf(s, aa, A[4]);
                    A[5] = fmaf(s, ab, A[5]);
                    A[6] = fmaf(s, ac, A[6]);
                    A[7] = fmaf(s, bb, A[7]);
                    A[8] = fmaf(s, bc, A[8]);
                    A[9] = fmaf(s, cc, A[9]);
                }
            }
        }
    }

    // role classes align at xor {4,8,16,32}: reduce wave -> lanes 0..3
    #pragma unroll
    for (int k = 0; k < 40; ++k) {
        float v = acc[k];
        v += __shfl_xor(v,  4, 64);
        v += __shfl_xor(v,  8, 64);
        v += __shfl_xor(v, 16, 64);
        v += __shfl_xor(v, 32, 64);
        acc[k] = v;
    }
    if (lane < 4) {                      // lane == mixture q; slot = q*40 + idx
        #pragma unroll
        for (int k = 0; k < 40; ++k) sred[wave][lane * 40 + k] = acc[k];
    }
    __syncthreads();
    if (tid < 160) {
        float s = sred[0][tid] + sred[1][tid] + sred[2][tid] + sred[3][tid];
        unsafeAtomicAdd(&sumsOut[tid * 4 + (blockIdx.x & 3)], s);  // HW fadd
    }
}

// ---------- final: all 16 gaussians -> logsumexp_g -> softmax_m ----------
__global__ __launch_bounds__(NTHR, 2) void k_final(const float* __restrict__ x,
                                                   const float* __restrict__ sumsIn,
                                                   float* __restrict__ out,
                                                   int N) {
    __shared__ __align__(16) float spar[192];
    __shared__ float sums[160];
    __shared__ float wtab[16];
    compute_params(sumsIn, spar, sums, wtab, threadIdx.x);
    const int lane = threadIdx.x & 63;
    const int q    = lane & 3;          // my role: mixture q
    const int qb   = lane & ~3;
    float PR[40];                        // my mixture's 4 gaussians x 10
    #pragma unroll
    for (int g = 0; g < 4; ++g)
        #pragma unroll
        for (int k = 0; k < 10; ++k) PR[g * 10 + k] = spar[q * 48 + g * 12 + k];

    const int groups = N >> 2;
    const int stride = gridDim.x * NTHR;
    const int gid    = blockIdx.x * NTHR + threadIdx.x;
    const int trips  = (groups + stride - 1) / stride;
    const float4* x0p = (const float4*)x;
    const float4* x1p = (const float4*)(x + N);
    const float4* x2p = (const float4*)(x + 2 * N);

    for (int tr = 0; tr < trips; ++tr) {
        const int i  = tr * stride + gid;
        const bool valid = i < groups;
        const int ii = valid ? i : 0;
        float4 va = x0p[ii], vb = x1p[ii], vc = x2p[ii];
        float pa[4] = {va.x, va.y, va.z, va.w};
        float pb[4] = {vb.x, vb.y, vb.z, vb.w};
        float pc[4] = {vc.x, vc.y, vc.z, vc.w};
        float po[4][4];                  // [j][mixture]

        #pragma unroll
        for (int j = 0; j < 4; ++j) {
            const float a = pa[j], b = pb[j], c = pc[j];
            float M[4];                  // ml_{my mixture}(quad pixel p)
            #pragma unroll
            for (int p = 0; p < 4; ++p) {
                const float ra = __shfl(a, qb + p, 64);
                const float rb = __shfl(b, qb + p, 64);
                const float rc = __shfl(c, qb + p, 64);
                const float aa = ra * ra, ab = ra * rb, ac = ra * rc;
                const float bb = rb * rb, bc = rb * rc, cc = rc * rc;
                float l[4];
                #pragma unroll
                for (int g = 0; g < 4; ++g) {
                    const float* P = &PR[g * 10];
                    l[g] = P[3] + P[0] * ra + P[1] * rb + P[2] * rc
                         + P[4] * aa + P[5] * bb + P[6] * cc
                         + P[7] * ab + P[8] * ac + P[9] * bc;
                }
                float mx = fmaxf(fmaxf(l[0], l[1]), fmaxf(l[2], l[3]));
                M[p] = mx + __logf(__expf(l[0] - mx) + __expf(l[1] - mx)
                                 + __expf(l[2] - mx) + __expf(l[3] - mx));
            }
            // 4x4 quad transpose: W[qq] = ml_{qq}(my own pixel, slot q)
            float W[4] = {0.f, 0.f, 0.f, 0.f};
            #pragma unroll
            for (int k = 0; k < 4; ++k) {
                #pragma unroll
                for (int qq = 0; qq < 4; ++qq) {
                    float v = __shfl(M[k], qb + qq, 64);
                    if (q == k) W[qq] = v;
                }
            }
            float mmx = fmaxf(fmaxf(W[0], W[1]), fmaxf(W[2], W[3]));
            float e0 = __expf(W[0] - mmx), e1 = __expf(W[1] - mmx);
            float e2 = __expf(W[2] - mmx), e3 = __expf(W[3] - mmx);
            float rs = 1.0f / (e0 + e1 + e2 + e3);
            po[j][0] = e0 * rs; po[j][1] = e1 * rs;
            po[j][2] = e2 * rs; po[j][3] = e3 * rs;
        }
        if (valid) {
            #pragma unroll
            for (int m = 0; m < 4; ++m) {
                ((float4*)(out + (size_t)m * N))[i] =
                    make_float4(po[0][m], po[1][m], po[2][m], po[3][m]);
            }
        }
    }
}

extern "C" void kernel_launch(void* const* d_in, const int* in_sizes, int n_in,
                              void* d_out, int out_size, void* d_ws, size_t ws_size,
                              hipStream_t stream) {
    const float* x   = (const float*)d_in[0];   // [3, N] float32
    const int*   lab = (const int*)d_in[1];     // [N] int32 in [0,4)
    float* out = (float*)d_out;                 // [4, N] float32
    const int N = in_sizes[1];

    float* sums = (float*)d_ws;                 // [3 passes][160 slots][4 banks]
    hipMemsetAsync(sums, 0, 3 * 640 * sizeof(float), stream);

    dim3 grid(NBLK), blk(NTHR);
    k_accum<<<grid, blk, 0, stream>>>(x, lab, sums, sums, N, 0);
    k_accum<<<grid, blk, 0, stream>>>(x, lab, sums, sums + 640, N, 1);
    k_accum<<<grid, blk, 0, stream>>>(x, lab, sums + 640, sums + 1280, N, 1);
    k_final<<<grid, blk, 0, stream>>>(x, sums + 1280, out, N);
}